// Round 25
// baseline (47.763 us; speedup 1.0000x reference)
//
#include <hip/hip_runtime.h>
#include <cstdint>

#define BATCH 8
#define T_SEQ 2048
#define E_DIM 1024
#define H_DIM 64
#define BT (BATCH * T_SEQ)

typedef __attribute__((ext_vector_type(8))) short bf16x8;   // 8 bf16 = 4 VGPR
typedef __attribute__((ext_vector_type(4))) float f32x4;

// fp32 -> bf16 bits, round-to-nearest-even
static __device__ __forceinline__ short f2bf(float f) {
    uint32_t b = __float_as_uint(f);
    b += 0x7fffu + ((b >> 16) & 1u);
    return (short)(b >> 16);
}

// 8 fp32 -> bf16x8 via packed RNE converts (same rounding as f2bf; HW-proven)
static __device__ __forceinline__ bf16x8 cvt8f(f32x4 a, f32x4 b) {
    union { bf16x8 v; uint32_t u[4]; } r;
    asm("v_cvt_pk_bf16_f32 %0, %1, %2" : "=v"(r.u[0]) : "v"(a.x), "v"(a.y));
    asm("v_cvt_pk_bf16_f32 %0, %1, %2" : "=v"(r.u[1]) : "v"(a.z), "v"(a.w));
    asm("v_cvt_pk_bf16_f32 %0, %1, %2" : "=v"(r.u[2]) : "v"(b.x), "v"(b.y));
    asm("v_cvt_pk_bf16_f32 %0, %1, %2" : "=v"(r.u[3]) : "v"(b.z), "v"(b.w));
    return r.v;
}

// ws element offsets (short units)
#define Q_OFF   0
#define K_OFF   (BT * H_DIM)                // kb frag-linear
#define VT_OFF  (2 * BT * H_DIM)            // vb frag-linear
#define WT_OFF  (3 * BT * H_DIM)            // wt_b frag-linear (384 KB)

static __device__ __forceinline__ void glds16(const void* g, void* l) {
    __builtin_amdgcn_global_load_lds(
        (const __attribute__((address_space(1))) void*)g,
        (__attribute__((address_space(3))) void*)l, 16, 0, 0);
}

// Fragment-linear layouts:
//   A-frag lane l: row = l&15, k = (l>>4)*8 + e
//   wt_b[f][kt][lane][8]       f = m*4+ct, col = ct*16+(l&15), kt = k/32
//   kb  [b][t][ct][s][lane][8] : K[token=t*64+ct*16+(l&15)][d=s*32+(l>>4)*8+e]
//   vb  [b][t][dt][s][lane][8] : V[token=t*64+s*32+(l>>4)*8+e][d=dt*16+(l&15)]

// ---- W -> wt_b (fragment-linear bf16) ----
__global__ void wt_prep_frag(const float* __restrict__ Wk, const float* __restrict__ Wq,
                             const float* __restrict__ Wv, short* __restrict__ wtb) {
    int gid = blockIdx.x * 256 + threadIdx.x;       // 0..24575
    int lane = gid & 63;
    int kt = (gid >> 6) & 31;
    int f = gid >> 11;                               // 0..11
    int m = f >> 2, ct = f & 3;
    int col = (ct << 4) | (lane & 15);
    int k0 = (kt << 5) | (((lane >> 4) & 3) << 3);
    const float* W = (m == 0) ? Wk : ((m == 1) ? Wq : Wv);
    bf16x8 v;
    #pragma unroll
    for (int e = 0; e < 8; ++e) v[e] = f2bf(W[(size_t)(k0 + e) * H_DIM + col]);
    *reinterpret_cast<bf16x8*>(wtb + (size_t)gid * 8) = v;
}

// ---- projection v6: BM=64, 512 thr (8 waves = 4 row-tiles x 2 k-halves) ----
// Same per-wave profile as R16-proven proj7 (12-frag acc, counted-vmcnt raw barriers),
// but wt staged ONCE per CU (halved L2 traffic) and single merge over 4 row-tiles.
__global__ __launch_bounds__(512) void proj8(
    const float* __restrict__ x, const short* __restrict__ wtb,
    short* __restrict__ qo, short* __restrict__ kb_, short* __restrict__ vb_)
{
    __shared__ __align__(16) short Bs[2][24 * 512];   // 2 x 24KB  B tiles (bf16)
    __shared__ __align__(16) float Xs[2][4096];       // 2 x 16KB  A tiles (fp32, swizzled)

    const int tid  = threadIdx.x;
    const int lane = tid & 63;
    const int w    = tid >> 6;           // 0..7
    const int rt   = w & 3;              // 16-row tile
    const int kh   = w >> 2;             // k-half (512 k each)
    const int row0 = blockIdx.x * 64;

    const f32x4 z4 = {0.f, 0.f, 0.f, 0.f};
    f32x4 acc[12];
    #pragma unroll
    for (int f = 0; f < 12; ++f) acc[f] = z4;

    // per stage a wave issues 3 B-glds + 2 A-glds = 5 vmem ops, all UNIFORM lds bases
    // A chunk ch (0..15): khs = ch>>3, cc = ch&7 -> rows cc*8+(lane>>3),
    //   granule (lane&7)^(lane>>3) of the 32-float step-slice (XOR pre-swizzled src)
    #define STAGE(dbuf, ss)                                                              \
        {                                                                                \
            _Pragma("unroll")                                                            \
            for (int ci = 0; ci < 3; ++ci) {                                             \
                int c = w * 3 + ci;                                                      \
                int f = c % 12, khc = c / 12;                                            \
                const short* src = wtb + (((size_t)f * 32 + khc * 16 + (ss)) * 64 + lane) * 8; \
                glds16(src, &Bs[dbuf][c * 512]);                                         \
            }                                                                            \
            _Pragma("unroll")                                                            \
            for (int i = 0; i < 2; ++i) {                                                \
                int ch = w * 2 + i;                                                      \
                int khs = ch >> 3, cc = ch & 7;                                          \
                const float* srcA = x + (size_t)(row0 + cc * 8 + (lane >> 3)) * E_DIM    \
                                      + khs * 512 + (ss) * 32                            \
                                      + (((lane & 7) ^ (lane >> 3)) << 2);               \
                glds16(srcA, &Xs[dbuf][ch * 256]);                                       \
            }                                                                            \
        }

    STAGE(0, 0);

    // read-side swizzle: slot = r8*8 + (j ^ r8) holds granule j of row-part r8
    const int r8  = lane & 7;
    const int j0  = (lane >> 4) << 1;
    const int chA = (kh << 3) | (rt << 1) | ((lane >> 3) & 1);
    const int g0  = r8 * 8 + (j0 ^ r8);
    const int g1  = r8 * 8 + ((j0 + 1) ^ r8);

    int buf = 0;
    for (int s = 0; s < 16; ++s) {
        if (s < 15) {
            STAGE(buf ^ 1, s + 1);
            asm volatile("s_waitcnt vmcnt(5)" ::: "memory");   // drain current buf only
        } else {
            asm volatile("s_waitcnt vmcnt(0)" ::: "memory");
        }
        __builtin_amdgcn_s_barrier();    // all waves' current-buf data landed

        f32x4 a = *reinterpret_cast<const f32x4*>(&Xs[buf][chA * 256 + g0 * 4]);
        f32x4 b = *reinterpret_cast<const f32x4*>(&Xs[buf][chA * 256 + g1 * 4]);
        bf16x8 afc = cvt8f(a, b);
        #pragma unroll
        for (int f = 0; f < 12; ++f) {
            bf16x8 bfv = *reinterpret_cast<const bf16x8*>(&Bs[buf][(kh * 12 + f) * 512 + lane * 8]);
            acc[f] = __builtin_amdgcn_mfma_f32_16x16x32_bf16(afc, bfv, acc[f], 0, 0, 0);
        }
        __builtin_amdgcn_s_barrier();    // all waves done reading buf before re-stage
        buf ^= 1;
    }

    // merge k-halves: mrg spans ALL of Bs (48KB) -> barrier before reuse
    __syncthreads();
    float* mrg = reinterpret_cast<float*>(&Bs[0][0]);
    if (kh == 1) {
        #pragma unroll
        for (int f = 0; f < 12; ++f)
            *reinterpret_cast<f32x4*>(mrg + ((size_t)(rt * 12 + f) * 64 + lane) * 4) = acc[f];
    }
    __syncthreads();
    if (kh == 0) {
        const int col16 = lane & 15, rowb = (lane >> 4) << 2;
        const int R0 = row0 + rt * 16 + rowb;
        #pragma unroll
        for (int m = 0; m < 3; ++m) {
            #pragma unroll
            for (int ct = 0; ct < 4; ++ct) {
                int f = m * 4 + ct;
                f32x4 v = acc[f];
                f32x4 o = *reinterpret_cast<const f32x4*>(mrg + ((size_t)(rt * 12 + f) * 64 + lane) * 4);
                v.x += o.x; v.y += o.y; v.z += o.z; v.w += o.w;
                int C = (ct << 4) | col16;
                #pragma unroll
                for (int i = 0; i < 4; ++i) {
                    int R = R0 + i;
                    int b = R >> 11, tok = R & 2047, tt = tok >> 6;
                    if (m == 1) {
                        qo[(size_t)R * H_DIM + C] = f2bf(v[i] * 0.125f);   // fold 1/sqrt(64)
                    } else if (m == 0) {
                        int ctk = (tok >> 4) & 3, lnk = (tok & 15) | (((C >> 3) & 3) << 4);
                        int sk = C >> 5, ek = C & 7;
                        kb_[(((((size_t)b * 32 + tt) * 4 + ctk) * 2 + sk) * 64 + lnk) * 8 + ek] = f2bf(v[i]);
                    } else {
                        int sv = (tok >> 5) & 1, gv = (tok >> 3) & 3, ev = tok & 7;
                        int dtv = C >> 4, lnv = (C & 15) | (gv << 4);
                        vb_[(((((size_t)b * 32 + tt) * 4 + dtv) * 2 + sv) * 64 + lnv) * 8 + ev] = f2bf(v[i]);
                    }
                }
            }
        }
    }
}

// ---- attention (R16/R24-proven attn3): barrier-free K-loop, frag-linear K/V from L2 ----
#define SWZ(row, off) ((off) ^ (((row) & 7) << 3))

__global__ __launch_bounds__(512, 4) void attn3(
    const short* __restrict__ q, const short* __restrict__ kb,
    const short* __restrict__ vb, float* __restrict__ out)
{
    __shared__ __align__(16) short Ps[8][16 * 64];     // per-wave, barrier-free
    __shared__ float Og[4][16][64];
    __shared__ float Mg[4][16], Lg[4][16];

    const int tid  = threadIdx.x;
    const int lane = tid & 63;
    const int w    = tid >> 6;          // 0..7
    const int band = w & 1;             // q sub-band (16 rows)
    const int kq   = w >> 1;            // 4-way split-K
    const int bb   = blockIdx.x & 7;
    const int j    = blockIdx.x >> 3;
    const int p    = (j < 32) ? (63 - j) : (j - 32);   // heavy+light pairing per CU

    const int q0 = p << 5;
    const int Nt = (p >> 1) + 1;

    const int qrowA = q0 + (band << 4) + (lane & 15);
    bf16x8 qf[2];
    #pragma unroll
    for (int s = 0; s < 2; ++s)
        qf[s] = *reinterpret_cast<const bf16x8*>(
            q + (size_t)(bb * T_SEQ + qrowA) * H_DIM + s * 32 + ((lane >> 4) << 3));

    const f32x4 z4 = {0.f, 0.f, 0.f, 0.f};
    float mreg[4] = {-1e30f, -1e30f, -1e30f, -1e30f};
    float lreg[4] = {0.f, 0.f, 0.f, 0.f};
    f32x4 oacc[4] = {z4, z4, z4, z4};

    const short* kbb = kb + (size_t)bb * 32 * 4096;
    const short* vbb = vb + (size_t)bb * 32 * 4096;

    for (int t = kq; t < Nt; t += 4) {
        const short* kt = kbb + (size_t)t * 4096 + lane * 8;
        // ---- S = Q . K^T ----
        f32x4 sacc[4] = {z4, z4, z4, z4};
        #pragma unroll
        for (int s = 0; s < 2; ++s)
            #pragma unroll
            for (int ct = 0; ct < 4; ++ct) {
                bf16x8 bfv = *reinterpret_cast<const bf16x8*>(kt + (ct * 2 + s) * 512);
                sacc[ct] = __builtin_amdgcn_mfma_f32_16x16x32_bf16(qf[s], bfv, sacc[ct], 0, 0, 0);
            }
        // ---- V preload (L2 latency hides under softmax) ----
        const short* vt_ = vbb + (size_t)t * 4096 + lane * 8;
        bf16x8 Vc[8];
        #pragma unroll
        for (int u = 0; u < 8; ++u)
            Vc[u] = *reinterpret_cast<const bf16x8*>(vt_ + u * 512);
        // ---- causal mask (only the diagonal tile) ----
        if (t == Nt - 1) {
            int qgb = q0 + (band << 4) + ((lane >> 4) << 2);
            #pragma unroll
            for (int ct = 0; ct < 4; ++ct) {
                int kg = t * 64 + (ct << 4) + (lane & 15);
                #pragma unroll
                for (int i = 0; i < 4; ++i)
                    if (kg > qgb + i) sacc[ct][i] = -1e30f;
            }
        }
        // ---- online softmax ----
        #pragma unroll
        for (int i = 0; i < 4; ++i) {
            float s0 = sacc[0][i], s1 = sacc[1][i], s2 = sacc[2][i], s3 = sacc[3][i];
            float tmax = fmaxf(fmaxf(s0, s1), fmaxf(s2, s3));
            tmax = fmaxf(tmax, __shfl_xor(tmax, 1));
            tmax = fmaxf(tmax, __shfl_xor(tmax, 2));
            tmax = fmaxf(tmax, __shfl_xor(tmax, 4));
            tmax = fmaxf(tmax, __shfl_xor(tmax, 8));
            float mnew = fmaxf(mreg[i], tmax);
            float sc = __expf(mreg[i] - mnew);
            mreg[i] = mnew;
            float p0 = __expf(s0 - mnew), p1 = __expf(s1 - mnew);
            float p2 = __expf(s2 - mnew), p3 = __expf(s3 - mnew);
            float ps = p0 + p1 + p2 + p3;
            ps += __shfl_xor(ps, 1); ps += __shfl_xor(ps, 2);
            ps += __shfl_xor(ps, 4); ps += __shfl_xor(ps, 8);
            lreg[i] = lreg[i] * sc + ps;
            oacc[0][i] *= sc; oacc[1][i] *= sc; oacc[2][i] *= sc; oacc[3][i] *= sc;
            int rq = ((lane >> 4) << 2) + i;
            short* pr = &Ps[w][rq * 64];
            pr[SWZ(rq, (0 << 4) + (lane & 15))] = f2bf(p0);
            pr[SWZ(rq, (1 << 4) + (lane & 15))] = f2bf(p1);
            pr[SWZ(rq, (2 << 4) + (lane & 15))] = f2bf(p2);
            pr[SWZ(rq, (3 << 4) + (lane & 15))] = f2bf(p3);
        }
        // ---- O += P . V ----
        int qa = lane & 15;
        #pragma unroll
        for (int dt = 0; dt < 4; ++dt)
            #pragma unroll
            for (int s = 0; s < 2; ++s) {
                int koff = s * 32 + ((lane >> 4) << 3);
                bf16x8 af = *reinterpret_cast<const bf16x8*>(&Ps[w][qa * 64 + SWZ(qa, koff)]);
                oacc[dt] = __builtin_amdgcn_mfma_f32_16x16x32_bf16(af, Vc[dt * 2 + s], oacc[dt], 0, 0, 0);
            }
    }

    // ---- merge the 4 split-K states per band ----
    __syncthreads();
    if (kq >= 2) {
        int slot = (band << 1) | (kq - 2);
        #pragma unroll
        for (int i = 0; i < 4; ++i) {
            int rq = ((lane >> 4) << 2) + i;
            #pragma unroll
            for (int dt = 0; dt < 4; ++dt)
                Og[slot][rq][(dt << 4) + (lane & 15)] = oacc[dt][i];
            if ((lane & 15) == 0) { Mg[slot][rq] = mreg[i]; Lg[slot][rq] = lreg[i]; }
        }
    }
    __syncthreads();
    if (kq < 2) {
        int slot = (band << 1) | kq;
        #pragma unroll
        for (int i = 0; i < 4; ++i) {
            int rq = ((lane >> 4) << 2) + i;
            float m1 = Mg[slot][rq], l1 = Lg[slot][rq];
            float mm = fmaxf(mreg[i], m1);
            float f0 = __expf(mreg[i] - mm), f1 = __expf(m1 - mm);
            mreg[i] = mm;
            lreg[i] = lreg[i] * f0 + l1 * f1;
            #pragma unroll
            for (int dt = 0; dt < 4; ++dt)
                oacc[dt][i] = oacc[dt][i] * f0 + Og[slot][rq][(dt << 4) + (lane & 15)] * f1;
        }
    }
    __syncthreads();
    if (kq == 1) {
        int slot = (band << 1) | 1;
        #pragma unroll
        for (int i = 0; i < 4; ++i) {
            int rq = ((lane >> 4) << 2) + i;
            #pragma unroll
            for (int dt = 0; dt < 4; ++dt)
                Og[slot][rq][(dt << 4) + (lane & 15)] = oacc[dt][i];
            if ((lane & 15) == 0) { Mg[slot][rq] = mreg[i]; Lg[slot][rq] = lreg[i]; }
        }
    }
    __syncthreads();
    if (kq == 0) {
        int slot = (band << 1) | 1;
        #pragma unroll
        for (int i = 0; i < 4; ++i) {
            int rq = ((lane >> 4) << 2) + i;
            float m1 = Mg[slot][rq], l1 = Lg[slot][rq];
            float mm = fmaxf(mreg[i], m1);
            float f0 = __expf(mreg[i] - mm), f1 = __expf(m1 - mm);
            float l  = lreg[i] * f0 + l1 * f1;
            float inv = 1.f / l;
            size_t orow = (size_t)(bb * T_SEQ + q0 + (band << 4) + rq) * H_DIM;
            #pragma unroll
            for (int dt = 0; dt < 4; ++dt) {
                float ov = oacc[dt][i] * f0 + Og[slot][rq][(dt << 4) + (lane & 15)] * f1;
                out[orow + (dt << 4) + (lane & 15)] = ov * inv;
            }
        }
    }
}

extern "C" void kernel_launch(void* const* d_in, const int* in_sizes, int n_in,
                              void* d_out, int out_size, void* d_ws, size_t ws_size,
                              hipStream_t stream) {
    const float* x  = (const float*)d_in[0];
    const float* Wk = (const float*)d_in[1];
    const float* Wq = (const float*)d_in[2];
    const float* Wv = (const float*)d_in[3];
    float* out = (float*)d_out;

    short* ws  = (short*)d_ws;
    short* qb  = ws + Q_OFF;
    short* kbp = ws + K_OFF;
    short* vbp = ws + VT_OFF;
    short* wtb = ws + WT_OFF;

    wt_prep_frag<<<96, 256, 0, stream>>>(Wk, Wq, Wv, wtb);
    proj8<<<BT / 64, 512, 0, stream>>>(x, wtb, qb, kbp, vbp);
    attn3<<<512, 512, 0, stream>>>(qb, kbp, vbp, out);
}

// Round 26
// 45.226 us; speedup vs baseline: 1.0561x; 1.0561x over previous
//
#include <hip/hip_runtime.h>
#include <cstdint>

#define BATCH 8
#define T_SEQ 2048
#define E_DIM 1024
#define H_DIM 64
#define BT (BATCH * T_SEQ)

typedef __attribute__((ext_vector_type(8))) short bf16x8;   // 8 bf16 = 4 VGPR
typedef __attribute__((ext_vector_type(4))) float f32x4;

// fp32 -> bf16 bits, round-to-nearest-even
static __device__ __forceinline__ short f2bf(float f) {
    uint32_t b = __float_as_uint(f);
    b += 0x7fffu + ((b >> 16) & 1u);
    return (short)(b >> 16);
}

// 8 fp32 -> bf16x8 via packed RNE converts (same rounding as f2bf; HW-proven)
static __device__ __forceinline__ bf16x8 cvt8f(f32x4 a, f32x4 b) {
    union { bf16x8 v; uint32_t u[4]; } r;
    asm("v_cvt_pk_bf16_f32 %0, %1, %2" : "=v"(r.u[0]) : "v"(a.x), "v"(a.y));
    asm("v_cvt_pk_bf16_f32 %0, %1, %2" : "=v"(r.u[1]) : "v"(a.z), "v"(a.w));
    asm("v_cvt_pk_bf16_f32 %0, %1, %2" : "=v"(r.u[2]) : "v"(b.x), "v"(b.y));
    asm("v_cvt_pk_bf16_f32 %0, %1, %2" : "=v"(r.u[3]) : "v"(b.z), "v"(b.w));
    return r.v;
}

// ws element offsets (short units)
#define Q_OFF   0
#define K_OFF   (BT * H_DIM)                // kb frag-linear
#define VT_OFF  (2 * BT * H_DIM)            // vb frag-linear
#define WT_OFF  (3 * BT * H_DIM)            // wt_b frag-linear (384 KB)

static __device__ __forceinline__ void glds16(const void* g, void* l) {
    __builtin_amdgcn_global_load_lds(
        (const __attribute__((address_space(1))) void*)g,
        (__attribute__((address_space(3))) void*)l, 16, 0, 0);
}

// Fragment-linear layouts:
//   A-frag lane l: row = l&15, k = (l>>4)*8 + e
//   wt_b[f][kt][lane][8]       f = m*4+ct, col = ct*16+(l&15), kt = k/32
//   kb  [b][t][ct][s][lane][8] : K[token=t*64+ct*16+(l&15)][d=s*32+(l>>4)*8+e]
//   vb  [b][t][dt][s][lane][8] : V[token=t*64+s*32+(l>>4)*8+e][d=dt*16+(l&15)]

// ---- W -> wt_b (fragment-linear bf16) ----
__global__ void wt_prep_frag(const float* __restrict__ Wk, const float* __restrict__ Wq,
                             const float* __restrict__ Wv, short* __restrict__ wtb) {
    int gid = blockIdx.x * 256 + threadIdx.x;       // 0..24575
    int lane = gid & 63;
    int kt = (gid >> 6) & 31;
    int f = gid >> 11;                               // 0..11
    int m = f >> 2, ct = f & 3;
    int col = (ct << 4) | (lane & 15);
    int k0 = (kt << 5) | (((lane >> 4) & 3) << 3);
    const float* W = (m == 0) ? Wk : ((m == 1) ? Wq : Wv);
    bf16x8 v;
    #pragma unroll
    for (int e = 0; e < 8; ++e) v[e] = f2bf(W[(size_t)(k0 + e) * H_DIM + col]);
    *reinterpret_cast<bf16x8*>(wtb + (size_t)gid * 8) = v;
}

// ---- projection (R16/R24-proven): all-glds staging, counted-vmcnt raw barriers ----
__global__ __launch_bounds__(256, 2) void proj7(
    const float* __restrict__ x, const short* __restrict__ wtb,
    short* __restrict__ qo, short* __restrict__ kb_, short* __restrict__ vb_)
{
    __shared__ __align__(16) short Bs[2][24 * 512];   // 2 x 24KB  B tiles (bf16)
    __shared__ __align__(16) float Xs[2][2048];       // 2 x 8KB   A tiles (fp32, swizzled)

    const int tid  = threadIdx.x;
    const int lane = tid & 63;
    const int w    = tid >> 6;
    const int kh   = w >> 1;             // k-half (512 k each)
    const int rtl  = w & 1;              // row-tile within block
    const int rt_g = blockIdx.x * 2 + rtl;
    const int row0 = blockIdx.x * 32;

    const f32x4 z4 = {0.f, 0.f, 0.f, 0.f};
    f32x4 acc[12];
    #pragma unroll
    for (int f = 0; f < 12; ++f) acc[f] = z4;

    #define STAGE(dbuf, ss)                                                              \
        {                                                                                \
            _Pragma("unroll")                                                            \
            for (int ci = 0; ci < 6; ++ci) {                                             \
                int c = w * 6 + ci;                                                      \
                int f = c % 12, khc = c / 12;                                            \
                const short* src = wtb + (((size_t)f * 32 + khc * 16 + (ss)) * 64 + lane) * 8; \
                glds16(src, &Bs[dbuf][c * 512]);                                         \
            }                                                                            \
            _Pragma("unroll")                                                            \
            for (int i = 0; i < 2; ++i) {                                                \
                int ch = w * 2 + i;                                                      \
                int slc = ch >> 2, cc = ch & 3;                                          \
                const float* srcA = x + (size_t)(row0 + cc * 8 + (lane >> 3)) * E_DIM    \
                                      + slc * 512 + (ss) * 32                            \
                                      + (((lane & 7) ^ (lane >> 3)) << 2);               \
                glds16(srcA, &Xs[dbuf][ch * 256]);                                       \
            }                                                                            \
        }

    STAGE(0, 0);

    const int r8  = lane & 7;
    const int j0  = (lane >> 4) << 1;
    const int chA = (kh << 2) | (rtl << 1) | ((lane >> 3) & 1);
    const int g0  = r8 * 8 + (j0 ^ r8);
    const int g1  = r8 * 8 + ((j0 + 1) ^ r8);

    int buf = 0;
    for (int s = 0; s < 16; ++s) {
        if (s < 15) {
            STAGE(buf ^ 1, s + 1);
            asm volatile("s_waitcnt vmcnt(8)" ::: "memory");   // drain current buf only
        } else {
            asm volatile("s_waitcnt vmcnt(0)" ::: "memory");
        }
        __builtin_amdgcn_s_barrier();    // all waves' current-buf data landed

        f32x4 a = *reinterpret_cast<const f32x4*>(&Xs[buf][chA * 256 + g0 * 4]);
        f32x4 b = *reinterpret_cast<const f32x4*>(&Xs[buf][chA * 256 + g1 * 4]);
        bf16x8 afc = cvt8f(a, b);
        #pragma unroll
        for (int f = 0; f < 12; ++f) {
            bf16x8 bfv = *reinterpret_cast<const bf16x8*>(&Bs[buf][(kh * 12 + f) * 512 + lane * 8]);
            acc[f] = __builtin_amdgcn_mfma_f32_16x16x32_bf16(afc, bfv, acc[f], 0, 0, 0);
        }
        __builtin_amdgcn_s_barrier();    // all waves done reading buf before re-stage
        buf ^= 1;
    }

    // merge k-halves (mrg aliases Bs[0]; last MFMA reads were Bs[1])
    float* mrg = reinterpret_cast<float*>(&Bs[0][0]);
    if (kh == 1) {
        #pragma unroll
        for (int f = 0; f < 12; ++f)
            *reinterpret_cast<f32x4*>(mrg + ((size_t)(rtl * 12 + f) * 64 + lane) * 4) = acc[f];
    }
    __syncthreads();
    if (kh == 0) {
        const int col16 = lane & 15, rowb = (lane >> 4) << 2;
        const int R0 = rt_g * 16 + rowb;
        #pragma unroll
        for (int m = 0; m < 3; ++m) {
            #pragma unroll
            for (int ct = 0; ct < 4; ++ct) {
                int f = m * 4 + ct;
                f32x4 v = acc[f];
                f32x4 o = *reinterpret_cast<const f32x4*>(mrg + ((size_t)(rtl * 12 + f) * 64 + lane) * 4);
                v.x += o.x; v.y += o.y; v.z += o.z; v.w += o.w;
                int C = (ct << 4) | col16;
                #pragma unroll
                for (int i = 0; i < 4; ++i) {
                    int R = R0 + i;
                    int b = R >> 11, tok = R & 2047, tt = tok >> 6;
                    if (m == 1) {
                        qo[(size_t)R * H_DIM + C] = f2bf(v[i] * 0.125f);   // fold 1/sqrt(64)
                    } else if (m == 0) {
                        int ctk = (tok >> 4) & 3, lnk = (tok & 15) | (((C >> 3) & 3) << 4);
                        int sk = C >> 5, ek = C & 7;
                        kb_[(((((size_t)b * 32 + tt) * 4 + ctk) * 2 + sk) * 64 + lnk) * 8 + ek] = f2bf(v[i]);
                    } else {
                        int sv = (tok >> 5) & 1, gv = (tok >> 3) & 3, ev = tok & 7;
                        int dtv = C >> 4, lnv = (C & 15) | (gv << 4);
                        vb_[(((((size_t)b * 32 + tt) * 4 + dtv) * 2 + sv) * 64 + lnv) * 8 + ev] = f2bf(v[i]);
                    }
                }
            }
        }
    }
}

// ---- attention (R16/R24-proven attn3): barrier-free K-loop, frag-linear K/V from L2 ----
#define SWZ(row, off) ((off) ^ (((row) & 7) << 3))

__global__ __launch_bounds__(512, 4) void attn3(
    const short* __restrict__ q, const short* __restrict__ kb,
    const short* __restrict__ vb, float* __restrict__ out)
{
    __shared__ __align__(16) short Ps[8][16 * 64];     // per-wave, barrier-free
    __shared__ float Og[4][16][64];
    __shared__ float Mg[4][16], Lg[4][16];

    const int tid  = threadIdx.x;
    const int lane = tid & 63;
    const int w    = tid >> 6;          // 0..7
    const int band = w & 1;             // q sub-band (16 rows)
    const int kq   = w >> 1;            // 4-way split-K
    const int bb   = blockIdx.x & 7;
    const int j    = blockIdx.x >> 3;
    const int p    = (j < 32) ? (63 - j) : (j - 32);   // heavy+light pairing per CU

    const int q0 = p << 5;
    const int Nt = (p >> 1) + 1;

    const int qrowA = q0 + (band << 4) + (lane & 15);
    bf16x8 qf[2];
    #pragma unroll
    for (int s = 0; s < 2; ++s)
        qf[s] = *reinterpret_cast<const bf16x8*>(
            q + (size_t)(bb * T_SEQ + qrowA) * H_DIM + s * 32 + ((lane >> 4) << 3));

    const f32x4 z4 = {0.f, 0.f, 0.f, 0.f};
    float mreg[4] = {-1e30f, -1e30f, -1e30f, -1e30f};
    float lreg[4] = {0.f, 0.f, 0.f, 0.f};
    f32x4 oacc[4] = {z4, z4, z4, z4};

    const short* kbb = kb + (size_t)bb * 32 * 4096;
    const short* vbb = vb + (size_t)bb * 32 * 4096;

    for (int t = kq; t < Nt; t += 4) {
        const short* kt = kbb + (size_t)t * 4096 + lane * 8;
        // ---- S = Q . K^T ----
        f32x4 sacc[4] = {z4, z4, z4, z4};
        #pragma unroll
        for (int s = 0; s < 2; ++s)
            #pragma unroll
            for (int ct = 0; ct < 4; ++ct) {
                bf16x8 bfv = *reinterpret_cast<const bf16x8*>(kt + (ct * 2 + s) * 512);
                sacc[ct] = __builtin_amdgcn_mfma_f32_16x16x32_bf16(qf[s], bfv, sacc[ct], 0, 0, 0);
            }
        // ---- V preload (L2 latency hides under softmax) ----
        const short* vt_ = vbb + (size_t)t * 4096 + lane * 8;
        bf16x8 Vc[8];
        #pragma unroll
        for (int u = 0; u < 8; ++u)
            Vc[u] = *reinterpret_cast<const bf16x8*>(vt_ + u * 512);
        // ---- causal mask (only the diagonal tile) ----
        if (t == Nt - 1) {
            int qgb = q0 + (band << 4) + ((lane >> 4) << 2);
            #pragma unroll
            for (int ct = 0; ct < 4; ++ct) {
                int kg = t * 64 + (ct << 4) + (lane & 15);
                #pragma unroll
                for (int i = 0; i < 4; ++i)
                    if (kg > qgb + i) sacc[ct][i] = -1e30f;
            }
        }
        // ---- online softmax ----
        #pragma unroll
        for (int i = 0; i < 4; ++i) {
            float s0 = sacc[0][i], s1 = sacc[1][i], s2 = sacc[2][i], s3 = sacc[3][i];
            float tmax = fmaxf(fmaxf(s0, s1), fmaxf(s2, s3));
            tmax = fmaxf(tmax, __shfl_xor(tmax, 1));
            tmax = fmaxf(tmax, __shfl_xor(tmax, 2));
            tmax = fmaxf(tmax, __shfl_xor(tmax, 4));
            tmax = fmaxf(tmax, __shfl_xor(tmax, 8));
            float mnew = fmaxf(mreg[i], tmax);
            float sc = __expf(mreg[i] - mnew);
            mreg[i] = mnew;
            float p0 = __expf(s0 - mnew), p1 = __expf(s1 - mnew);
            float p2 = __expf(s2 - mnew), p3 = __expf(s3 - mnew);
            float ps = p0 + p1 + p2 + p3;
            ps += __shfl_xor(ps, 1); ps += __shfl_xor(ps, 2);
            ps += __shfl_xor(ps, 4); ps += __shfl_xor(ps, 8);
            lreg[i] = lreg[i] * sc + ps;
            oacc[0][i] *= sc; oacc[1][i] *= sc; oacc[2][i] *= sc; oacc[3][i] *= sc;
            int rq = ((lane >> 4) << 2) + i;
            short* pr = &Ps[w][rq * 64];
            pr[SWZ(rq, (0 << 4) + (lane & 15))] = f2bf(p0);
            pr[SWZ(rq, (1 << 4) + (lane & 15))] = f2bf(p1);
            pr[SWZ(rq, (2 << 4) + (lane & 15))] = f2bf(p2);
            pr[SWZ(rq, (3 << 4) + (lane & 15))] = f2bf(p3);
        }
        // ---- O += P . V ----
        int qa = lane & 15;
        #pragma unroll
        for (int dt = 0; dt < 4; ++dt)
            #pragma unroll
            for (int s = 0; s < 2; ++s) {
                int koff = s * 32 + ((lane >> 4) << 3);
                bf16x8 af = *reinterpret_cast<const bf16x8*>(&Ps[w][qa * 64 + SWZ(qa, koff)]);
                oacc[dt] = __builtin_amdgcn_mfma_f32_16x16x32_bf16(af, Vc[dt * 2 + s], oacc[dt], 0, 0, 0);
            }
    }

    // ---- merge the 4 split-K states per band ----
    __syncthreads();
    if (kq >= 2) {
        int slot = (band << 1) | (kq - 2);
        #pragma unroll
        for (int i = 0; i < 4; ++i) {
            int rq = ((lane >> 4) << 2) + i;
            #pragma unroll
            for (int dt = 0; dt < 4; ++dt)
                Og[slot][rq][(dt << 4) + (lane & 15)] = oacc[dt][i];
            if ((lane & 15) == 0) { Mg[slot][rq] = mreg[i]; Lg[slot][rq] = lreg[i]; }
        }
    }
    __syncthreads();
    if (kq < 2) {
        int slot = (band << 1) | kq;
        #pragma unroll
        for (int i = 0; i < 4; ++i) {
            int rq = ((lane >> 4) << 2) + i;
            float m1 = Mg[slot][rq], l1 = Lg[slot][rq];
            float mm = fmaxf(mreg[i], m1);
            float f0 = __expf(mreg[i] - mm), f1 = __expf(m1 - mm);
            mreg[i] = mm;
            lreg[i] = lreg[i] * f0 + l1 * f1;
            #pragma unroll
            for (int dt = 0; dt < 4; ++dt)
                oacc[dt][i] = oacc[dt][i] * f0 + Og[slot][rq][(dt << 4) + (lane & 15)] * f1;
        }
    }
    __syncthreads();
    if (kq == 1) {
        int slot = (band << 1) | 1;
        #pragma unroll
        for (int i = 0; i < 4; ++i) {
            int rq = ((lane >> 4) << 2) + i;
            #pragma unroll
            for (int dt = 0; dt < 4; ++dt)
                Og[slot][rq][(dt << 4) + (lane & 15)] = oacc[dt][i];
            if ((lane & 15) == 0) { Mg[slot][rq] = mreg[i]; Lg[slot][rq] = lreg[i]; }
        }
    }
    __syncthreads();
    if (kq == 0) {
        int slot = (band << 1) | 1;
        #pragma unroll
        for (int i = 0; i < 4; ++i) {
            int rq = ((lane >> 4) << 2) + i;
            float m1 = Mg[slot][rq], l1 = Lg[slot][rq];
            float mm = fmaxf(mreg[i], m1);
            float f0 = __expf(mreg[i] - mm), f1 = __expf(m1 - mm);
            float l  = lreg[i] * f0 + l1 * f1;
            float inv = 1.f / l;
            size_t orow = (size_t)(bb * T_SEQ + q0 + (band << 4) + rq) * H_DIM;
            #pragma unroll
            for (int dt = 0; dt < 4; ++dt) {
                float ov = oacc[dt][i] * f0 + Og[slot][rq][(dt << 4) + (lane & 15)] * f1;
                out[orow + (dt << 4) + (lane & 15)] = ov * inv;
            }
        }
    }
}

extern "C" void kernel_launch(void* const* d_in, const int* in_sizes, int n_in,
                              void* d_out, int out_size, void* d_ws, size_t ws_size,
                              hipStream_t stream) {
    const float* x  = (const float*)d_in[0];
    const float* Wk = (const float*)d_in[1];
    const float* Wq = (const float*)d_in[2];
    const float* Wv = (const float*)d_in[3];
    float* out = (float*)d_out;

    short* ws  = (short*)d_ws;
    short* qb  = ws + Q_OFF;
    short* kbp = ws + K_OFF;
    short* vbp = ws + VT_OFF;
    short* wtb = ws + WT_OFF;

    wt_prep_frag<<<96, 256, 0, stream>>>(Wk, Wq, Wv, wtb);
    proj7<<<BT / 32, 256, 0, stream>>>(x, wtb, qb, kbp, vbp);
    attn3<<<512, 512, 0, stream>>>(qb, kbp, vbp, out);
}